// Round 5
// baseline (389.480 us; speedup 1.0000x reference)
//
#include <hip/hip_runtime.h>

#define SEQ 4096
#define DMODEL 1024
#define DSTATE 64
#define DINNER 2048
#define MROWS 8192            // BATCH*SEQ
#define NCAT 1152             // 1024 (dt) + 64 (xp) + 64 pad
#define NCHUNK 64             // scan chunks
#define LCHUNK 64             // steps per chunk

typedef __attribute__((ext_vector_type(8))) __bf16 bf16x8;
typedef __attribute__((ext_vector_type(8))) short short8;
typedef __attribute__((ext_vector_type(4))) float floatx4;

__device__ inline float bf2f(short s) {
  union { unsigned u; float f; } c;
  c.u = ((unsigned)(unsigned short)s) << 16;
  return c.f;
}
__device__ inline short f2bf(float f) {
  union { float f; unsigned u; } c; c.f = f;
  unsigned r = 0x7fffu + ((c.u >> 16) & 1u);
  return (short)((c.u + r) >> 16);
}
__device__ inline float silu_f(float v) {
  return v * __builtin_amdgcn_rcpf(1.f + __expf(-v));
}
__device__ inline float softplus_f(float v) {
  return fmaxf(v, 0.f) + log1pf(__expf(-fabsf(v)));
}
// async global->LDS, 16B per lane. LDS dest = wave-uniform base + lane*16.
__device__ inline void gld_lds16(const void* g, void* l) {
  __builtin_amdgcn_global_load_lds(
      (__attribute__((address_space(1))) void*)g,
      (__attribute__((address_space(3))) void*)l, 16, 0, 0);
}

// panel-staged bf16 layout: panel = 16 rows, stored contiguously (K*32 bytes),
// inside: [k-chunk of 8][row-in-panel 16][8 elems].  element (r,k):
__device__ inline size_t permOff(int r, int k, int K) {
  return (((size_t)(r >> 4) * (K >> 3) + (k >> 3)) << 7) + ((r & 15) << 3) + (k & 7);
}

// ---------------- fused pre-pass ---------------------------------------------
#define PP0 4096
#define PP1 (PP0 + 4096)
#define PP2 (PP1 + 2048)
#define PP3 (PP2 + 128)
#define PP4 (PP3 + 2048)

__device__ void tile_transpose_perm(const float* __restrict__ in, short* __restrict__ out,
                                    int R, int C, int bx, int by, float (*tile)[33]) {
  const int tx = threadIdx.x & 31, ty = threadIdx.x >> 5;   // 32 x 8
  const int cb = bx * 32, rb = by * 32;
#pragma unroll
  for (int i = 0; i < 32; i += 8) {
    int r = rb + ty + i, c = cb + tx;
    tile[ty + i][tx] = (r < R && c < C) ? in[(size_t)r * C + c] : 0.f;
  }
  __syncthreads();
#pragma unroll
  for (int i = 0; i < 32; i += 8) {
    int orow = cb + ty + i, oc = rb + tx;   // out(row=orow, k=oc) = in[oc][orow]
    if (orow < C && oc < R) out[permOff(orow, oc, R)] = f2bf(tile[tx][ty + i]);
  }
}

__global__ void prepass_kernel(const float* __restrict__ x, short* __restrict__ x_bf,
                               const float* __restrict__ W_in, short* __restrict__ Wt_in,
                               const float* __restrict__ W_dt, const float* __restrict__ W_xp,
                               short* __restrict__ Bcat,
                               const float* __restrict__ W_out, short* __restrict__ Wt_out) {
  __shared__ float tile[32][33];
  const int blk = blockIdx.x;
  if (blk < PP0) {
    int o = blk * 256 + threadIdx.x;            // [0, 1M) 16B groups
    int m = o & 15, rest = o >> 4;
    int c = rest & 127, p = rest >> 7;          // K/8 = 128 chunks
    const float* src = x + ((size_t)(p * 16 + m)) * 1024 + c * 8;
    float4 v0 = ((const float4*)src)[0];
    float4 v1 = ((const float4*)src)[1];
    short8 ov;
    ov[0] = f2bf(v0.x); ov[1] = f2bf(v0.y); ov[2] = f2bf(v0.z); ov[3] = f2bf(v0.w);
    ov[4] = f2bf(v1.x); ov[5] = f2bf(v1.y); ov[6] = f2bf(v1.z); ov[7] = f2bf(v1.w);
    ((short8*)x_bf)[o] = ov;
  } else if (blk < PP1) {
    int t = blk - PP0;
    tile_transpose_perm(W_in, Wt_in, 1024, 4096, t & 127, t >> 7, tile);
  } else if (blk < PP2) {
    int t = blk - PP1;
    tile_transpose_perm(W_dt, Bcat, 2048, 1024, t & 31, t >> 5, tile);
  } else if (blk < PP3) {
    int t = blk - PP2;
    tile_transpose_perm(W_xp, Bcat + (size_t)1024 * DINNER, 2048, 64, t & 1, t >> 1, tile);
  } else {
    int t = blk - PP3;
    tile_transpose_perm(W_out, Wt_out, 2048, 1024, t & 31, t >> 5, tile);
  }
}

// ---------------- bf16 GEMM, BK=64 (legacy 128x128 structure; GEMM2 only) ----
template <int MODE, int KTOT, int KSL, int NB, int Z>
__global__ __launch_bounds__(256) void gemm_bt(
    const short* __restrict__ A, const short* __restrict__ Bt,
    const float* __restrict__ bias,
    void* __restrict__ out0, void* __restrict__ out1)
{
  __shared__ __attribute__((aligned(16))) short sA[128 * 64];
  __shared__ __attribute__((aligned(16))) short sB[128 * 64];

  const int tid = threadIdx.x;
  const int lane = tid & 63;
  const int w = tid >> 6;          // wave 0..3
  const int wr = w >> 1, wc = w & 1;
  const int m = lane & 15, quad = lane >> 4;

  const int xcd = blockIdx.x & 7;
  const int rest = blockIdx.x >> 3;
  constexpr int PXB = 8 * NB;               // blocks per XCD per z-slice
  const int z = rest / PXB;
  const int q2 = rest - z * PXB;
  const int bM = (xcd * 8 + (q2 & 7)) * 128;
  const int bN = (q2 >> 3) * 128;
  constexpr int N = NB * 128;

  floatx4 acc[4][4] = {};

  const size_t PS = (size_t)KTOT * 16;            // panel stride (shorts)
  const short* Apan0 = A  + ((size_t)(bM >> 4) + w) * PS + lane * 8;
  const short* Apan1 = Apan0 + 4 * PS;
  const short* Bpan0 = Bt + ((size_t)(bN >> 4) + w) * PS + lane * 8;
  const short* Bpan1 = Bpan0 + 4 * PS;
  short* dA0 = sA + w * 1024;
  short* dA1 = sA + (w + 4) * 1024;
  short* dB0 = sB + w * 1024;
  short* dB1 = sB + (w + 4) * 1024;

  const int kbeg = z * KSL;
  for (int k0 = kbeg; k0 < kbeg + KSL; k0 += 64) {
    __syncthreads();
    const size_t ko = (size_t)k0 * 16;            // 64 k -> 2048 shorts per panel
    gld_lds16(Apan0 + ko,       dA0);
    gld_lds16(Apan0 + ko + 512, dA0 + 512);
    gld_lds16(Apan1 + ko,       dA1);
    gld_lds16(Apan1 + ko + 512, dA1 + 512);
    gld_lds16(Bpan0 + ko,       dB0);
    gld_lds16(Bpan0 + ko + 512, dB0 + 512);
    gld_lds16(Bpan1 + ko,       dB1);
    gld_lds16(Bpan1 + ko + 512, dB1 + 512);
    __syncthreads();   // drains vmcnt incl. global_load_lds
#pragma unroll
    for (int kh = 0; kh < 2; ++kh) {
      bf16x8 af[4], bf[4];
#pragma unroll
      for (int rt = 0; rt < 4; ++rt)
        af[rt] = *(const bf16x8*)(sA + (wr * 4 + rt) * 1024 + (kh * 4 + quad) * 128 + m * 8);
#pragma unroll
      for (int ct = 0; ct < 4; ++ct)
        bf[ct] = *(const bf16x8*)(sB + (wc * 4 + ct) * 1024 + (kh * 4 + quad) * 128 + m * 8);
#pragma unroll
      for (int rt = 0; rt < 4; ++rt)
#pragma unroll
        for (int ct = 0; ct < 4; ++ct)
          acc[rt][ct] = __builtin_amdgcn_mfma_f32_16x16x32_bf16(af[rt], bf[ct], acc[rt][ct], 0, 0, 0);
    }
  }

  const int rowbase = bM + wr * 64;
  const int colbase = bN + wc * 64;

  if (MODE == 0) {
    short* dst = (bN < DINNER) ? (short*)out0 : (short*)out1;
    const int cb = (bN < DINNER) ? colbase : colbase - DINNER;
#pragma unroll
    for (int rt = 0; rt < 4; ++rt) {
      const size_t rowPan = ((size_t)((rowbase >> 4) + rt)) << 8;   // *256 chunks
#pragma unroll
      for (int ct = 0; ct < 4; ++ct) {
        const int colA = colbase + ct * 16 + m;      // for bias
        const int colP = cb + ct * 16 + m;           // within 2048-wide target
        const size_t base = ((rowPan + (colP >> 3)) << 7) + (colP & 7) + ((size_t)quad * 32);
#pragma unroll
        for (int reg = 0; reg < 4; ++reg) {
          float val = acc[rt][ct][reg] + bias[colA];
          dst[base + reg * 8] = f2bf(silu_f(val));
        }
      }
    }
  } else {
    if (NB == 9 && colbase >= 1088) return;          // pad columns: drop
    short* dst = (short*)out0 + (size_t)z * MROWS * N;
#pragma unroll
    for (int rt = 0; rt < 4; ++rt)
#pragma unroll
      for (int ct = 0; ct < 4; ++ct) {
        const int col = colbase + ct * 16 + m;
#pragma unroll
        for (int reg = 0; reg < 4; ++reg) {
          const int r = rowbase + rt * 16 + quad * 4 + reg;
          dst[(size_t)r * N + col] = f2bf(acc[rt][ct][reg]);
        }
      }
  }
}

// ---------------- 256x256 read-ahead bf16 GEMM (counted-lgkm pipeline) -------
// 512 thr = 8 waves (2M x 4N); wave owns 128x64 = 8x4 frags of 16x16.
// BK=64, 2 LDS buffers x 64KB = 128KB -> 1 block/CU.
// KEY CHANGE vs round 4 (the m201 "[optional lgkmcnt(8)]" mechanism): the
// ds_read group for MFMA cluster k+1 is issued BEFORE cluster k's MFMAs, so
// the compiler's automatic waitcnt emits a COUNTED lgkmcnt (retiring only
// cluster k's operands) and the LDS port time of group k+1 overlaps cluster
// k's matrix-pipe time. Previously every cluster waited lgkmcnt(0): LDS port
// (~2300 cyc/tile/CU) and MFMA pipe (~2480 cyc/tile/SIMD) were serialized ->
// measured 6772 cyc/tile, 31.6% MfmaUtil.
// Clusters per K-tile: M0=kh0xrt0-3(accA), M1=kh0xrt4-7(accB),
// M2=kh1xrt0-3(accA), M3=kh1xrt4-7(accB). Read groups (per wave):
// G0={A-kh0 rt0-3, B-kh0}=8, G1={A-kh0 rt4-7}=4, G2={A-kh1 rt0-3, B-kh1}=8,
// G3={A-kh1 rt4-7}=4. Fragment regs double-buffered (aA,aB,bA,bB).
// Barriers: TWO per K-tile.
//  B_A(t) [phase A]: after per-wave lgkmcnt(0) (all buf(t-1) reads retired ->
//   WAR-safe for Q(t+1,*) stages) and after all waves' vmcnt(4) from phD(t-1)
//   (Q(t,0),Q(t,1) landed) -> G0(t) reads legal.
//  B_B(t) [phase C]: after per-wave lgkmcnt(0) + all waves' vmcnt(4) from
//   phB(t) (Q(t,2),Q(t,3) landed) -> G2(t) reads legal.
// vmcnt ledger (2 gld per stage-quarter, quarters staged one per phase):
//  phD(t-1) after stage Q(t,3): outstanding Q(t,0..3)=8 -> vmcnt(4) retires
//  Q(t,0),Q(t,1). phB(t) after stage Q(t+1,1): outstanding Q(t,2),Q(t,3),
//  Q(t+1,0),Q(t+1,1)=8 -> vmcnt(4) retires Q(t,2),Q(t,3). Tail: phB(KT-1)
//  has no stage -> vmcnt(0) retires the last 4. Never drains mid-pipeline.
template <int MODE, int KTOT, int KSL, int NT, int ZS>
__global__ __launch_bounds__(512, 2) void gemm256(
    const short* __restrict__ A, const short* __restrict__ Bt,
    const float* __restrict__ bias,
    void* __restrict__ out0, void* __restrict__ out1)
{
  __shared__ __attribute__((aligned(16))) short sLds[65536];   // 128 KiB

  const int tid = threadIdx.x;
  const int lane = tid & 63;
  const int w = tid >> 6;              // 0..7
  const int wr = w >> 2, wc = w & 3;   // 2 x 4 wave grid
  const int m = lane & 15, quad = lane >> 4;

  // XCD-aware 1D grid: each XCD owns a 4-M-tile stripe (A stays in its L2).
  const int xcd = blockIdx.x & 7;
  const int q = blockIdx.x >> 3;
  const int mt = xcd * 4 + (q & 3);
  const int rest = q >> 2;
  const int ntile = rest % NT;
  const int z = rest / NT;
  const int bM = mt * 256, bN = ntile * 256;
  const int kbeg = z * KSL;

  floatx4 acc[8][4] = {};

  const size_t PS = (size_t)KTOT * 16;   // panel stride in shorts
  const short* AgA = A  + ((size_t)(bM >> 4) + w) * PS + (size_t)kbeg * 16 + lane * 8;
  const short* AgB = AgA + 8 * PS;
  const short* BgA = Bt + ((size_t)(bN >> 4) + w) * PS + (size_t)kbeg * 16 + lane * 8;
  const short* BgB = BgA + 8 * PS;

  constexpr int KT = KSL / 64;           // K-tiles of 64 (>= 2)

  // LDS map (shorts): buf(t&1)*32768 + {A:0, B:16384} + kh*8192 + panel*512
  auto STAGE_Q = [&](int t, int qq) {    // quarter qq: 0:A-kh0 1:B-kh0 2:A-kh1 3:B-kh1
    const size_t go = (size_t)t * 1024 + (size_t)(qq >> 1) * 512;
    short* d = sLds + ((t & 1) << 15) + ((qq & 1) << 14) + ((qq >> 1) << 13) + w * 512;
    const short* g0 = (qq & 1) ? BgA : AgA;   // panel w
    const short* g1 = (qq & 1) ? BgB : AgB;   // panel w+8
    gld_lds16(g0 + go, d);
    gld_lds16(g1 + go, d + 4096);
  };

  const int aoff = wr * 4096 + quad * 128 + m * 8;           // + rt*512 + kh*8192
  const int boff = 16384 + wc * 2048 + quad * 128 + m * 8;   // + ct*512 + kh*8192

  bf16x8 aA[4], aB[4], bA[4], bB[4];

  // prologue: tile 0 fully staged; kh0 half waited; G0(0) issued
  STAGE_Q(0, 0); STAGE_Q(0, 1); STAGE_Q(0, 2); STAGE_Q(0, 3);
  asm volatile("s_waitcnt vmcnt(4)" ::: "memory");   // Q(0,0),Q(0,1) landed (mine)
  asm volatile("s_barrier" ::: "memory");            // B_A(0)
  {
    const short* bs = sLds;
#pragma unroll
    for (int rt = 0; rt < 4; ++rt) aA[rt] = *(const bf16x8*)(bs + aoff + rt * 512);
#pragma unroll
    for (int ct = 0; ct < 4; ++ct) bA[ct] = *(const bf16x8*)(bs + boff + ct * 512);
    if (KT > 1) STAGE_Q(1, 0);
    __builtin_amdgcn_sched_barrier(0);
  }

#pragma unroll 1
  for (int t = 0; t < KT; ++t) {
    const short* bs = sLds + ((t & 1) << 15);
    const bool pf = (t + 1 < KT);

    // ---- phase B: issue G1(t) | stage Q(t+1,1) | vmcnt | M0 (G0 ops, counted lgkm)
#pragma unroll
    for (int rt = 0; rt < 4; ++rt) aB[rt] = *(const bf16x8*)(bs + aoff + (4 + rt) * 512);
    if (pf) {
      STAGE_Q(t + 1, 1);
      asm volatile("s_waitcnt vmcnt(4)" ::: "memory");   // Q(t,2),Q(t,3) landed
    } else {
      asm volatile("s_waitcnt vmcnt(0)" ::: "memory");   // tail: last 4 stages
    }
    __builtin_amdgcn_sched_barrier(0);
    __builtin_amdgcn_s_setprio(1);
#pragma unroll
    for (int rt = 0; rt < 4; ++rt)
#pragma unroll
      for (int ct = 0; ct < 4; ++ct)
        acc[rt][ct] = __builtin_amdgcn_mfma_f32_16x16x32_bf16(aA[rt], bA[ct], acc[rt][ct], 0, 0, 0);
    __builtin_amdgcn_s_setprio(0);
    __builtin_amdgcn_sched_barrier(0);

    // ---- phase C: lgkm0+B_B(t) | issue G2(t) | stage Q(t+1,2) | M1 (G1+bA)
    asm volatile("s_waitcnt lgkmcnt(0)" ::: "memory");   // G1 retired (all reads done)
    asm volatile("s_barrier" ::: "memory");              // B_B(t): kh1 landed globally
#pragma unroll
    for (int rt = 0; rt < 4; ++rt) aA[rt] = *(const bf16x8*)(bs + 8192 + aoff + rt * 512);
#pragma unroll
    for (int ct = 0; ct < 4; ++ct) bB[ct] = *(const bf16x8*)(bs + 8192 + boff + ct * 512);
    if (pf) STAGE_Q(t + 1, 2);
    __builtin_amdgcn_sched_barrier(0);
    __builtin_amdgcn_s_setprio(1);
#pragma unroll
    for (int rt = 0; rt < 4; ++rt)
#pragma unroll
      for (int ct = 0; ct < 4; ++ct)
        acc[4 + rt][ct] = __builtin_amdgcn_mfma_f32_16x16x32_bf16(aB[rt], bA[ct], acc[4 + rt][ct], 0, 0, 0);
    __builtin_amdgcn_s_setprio(0);
    __builtin_amdgcn_sched_barrier(0);

    // ---- phase D: issue G3(t) | stage Q(t+1,3) | vmcnt | M2 (G2 ops, counted lgkm)
#pragma unroll
    for (int rt = 0; rt < 4; ++rt) aB[rt] = *(const bf16x8*)(bs + 8192 + aoff + (4 + rt) * 512);
    if (pf) {
      STAGE_Q(t + 1, 3);
      asm volatile("s_waitcnt vmcnt(4)" ::: "memory");   // Q(t+1,0),Q(t+1,1) landed
    }
    __builtin_amdgcn_sched_barrier(0);
    __builtin_amdgcn_s_setprio(1);
#pragma unroll
    for (int rt = 0; rt < 4; ++rt)
#pragma unroll
      for (int ct = 0; ct < 4; ++ct)
        acc[rt][ct] = __builtin_amdgcn_mfma_f32_16x16x32_bf16(aA[rt], bB[ct], acc[rt][ct], 0, 0, 0);
    __builtin_amdgcn_s_setprio(0);
    __builtin_amdgcn_sched_barrier(0);

    // ---- phase A(t+1): lgkm0+B_A | issue G0(t+1) | stage Q(t+2,0)
    if (pf) {
      asm volatile("s_waitcnt lgkmcnt(0)" ::: "memory"); // G3 retired: WAR-safe
      asm volatile("s_barrier" ::: "memory");            // B_A(t+1)
      const short* bs2 = sLds + (((t + 1) & 1) << 15);
#pragma unroll
      for (int rt = 0; rt < 4; ++rt) aA[rt] = *(const bf16x8*)(bs2 + aoff + rt * 512);
#pragma unroll
      for (int ct = 0; ct < 4; ++ct) bA[ct] = *(const bf16x8*)(bs2 + boff + ct * 512);
      if (t + 2 < KT) STAGE_Q(t + 2, 0);
      __builtin_amdgcn_sched_barrier(0);
    }
    // ---- M3(t): G3 x G2's B (operands already retired or auto-waited)
    __builtin_amdgcn_s_setprio(1);
#pragma unroll
    for (int rt = 0; rt < 4; ++rt)
#pragma unroll
      for (int ct = 0; ct < 4; ++ct)
        acc[4 + rt][ct] = __builtin_amdgcn_mfma_f32_16x16x32_bf16(aB[rt], bB[ct], acc[4 + rt][ct], 0, 0, 0);
    __builtin_amdgcn_s_setprio(0);
    __builtin_amdgcn_sched_barrier(0);
  }

  const int rowbase = bM + wr * 128;
  const int colbase = bN + wc * 64;

  if constexpr (MODE == 0) {
    // silu epilogue, panel-staged out; 256-wide tiles never straddle DINNER.
    short* dst = (bN < DINNER) ? (short*)out0 : (short*)out1;
    const int cb = (bN < DINNER) ? colbase : colbase - DINNER;
#pragma unroll
    for (int rt = 0; rt < 8; ++rt) {
      const size_t rowPan = ((size_t)(rowbase >> 4) + rt) << 8;   // *256 chunks
#pragma unroll
      for (int ct = 0; ct < 4; ++ct) {
        const int colA = colbase + ct * 16 + m;
        const int colP = cb + ct * 16 + m;
        const size_t base = ((rowPan + (colP >> 3)) << 7) + (colP & 7) + ((size_t)quad * 32);
        const float bv = bias[colA];
#pragma unroll
        for (int reg = 0; reg < 4; ++reg) {
          float val = acc[rt][ct][reg] + bv;
          dst[base + reg * 8] = f2bf(silu_f(val));
        }
      }
    }
  } else {
    // raw bf16 partials, row-major stride N, +z slice offset
    constexpr int N = NT * 256;
    short* dst = (short*)out0 + (size_t)z * MROWS * N;
#pragma unroll
    for (int rt = 0; rt < 8; ++rt)
#pragma unroll
      for (int ct = 0; ct < 4; ++ct) {
        const int col = colbase + ct * 16 + m;
#pragma unroll
        for (int reg = 0; reg < 4; ++reg) {
          const int r = rowbase + rt * 16 + quad * 4 + reg;
          dst[(size_t)r * N + col] = f2bf(acc[rt][ct][reg]);
        }
      }
  }
}

// ---------------- split-K combine epilogues ----------------------------------
// G2: one wave per row; p[2][8192][1152] bf16 -> md_sum, bx
__global__ void g2_epilogue(const short* __restrict__ p, const float* __restrict__ b_dt,
                            const float* __restrict__ b_xp,
                            float* __restrict__ md_sum, float* __restrict__ bx) {
  const int row = blockIdx.x * 4 + (threadIdx.x >> 6);
  const int lane = threadIdx.x & 63;
  const size_t base0 = (size_t)row * NCAT;
  const size_t base1 = base0 + (size_t)MROWS * NCAT;
  short8 a0 = *(const short8*)(p + base0 + lane * 16);
  short8 a1 = *(const short8*)(p + base0 + lane * 16 + 8);
  short8 c0 = *(const short8*)(p + base1 + lane * 16);
  short8 c1 = *(const short8*)(p + base1 + lane * 16 + 8);
  float s = 0.f;
#pragma unroll
  for (int j = 0; j < 8; ++j) {
    s += softplus_f(bf2f(a0[j]) + bf2f(c0[j]) + b_dt[lane * 16 + j]);
    s += softplus_f(bf2f(a1[j]) + bf2f(c1[j]) + b_dt[lane * 16 + 8 + j]);
  }
  s += __shfl_xor(s, 1);  s += __shfl_xor(s, 2);  s += __shfl_xor(s, 4);
  s += __shfl_xor(s, 8);  s += __shfl_xor(s, 16); s += __shfl_xor(s, 32);
  if (lane == 0) md_sum[row] = s;
  bx[(size_t)row * DSTATE + lane] =
      bf2f(p[base0 + 1024 + lane]) + bf2f(p[base1 + 1024 + lane]) + b_xp[lane];
}

// G4: out = p0 + p1 + b_out + x*D   (fp32 row-major [8192,1024])
__global__ void g4_epilogue(const short* __restrict__ p, const float* __restrict__ b_out,
                            const float* __restrict__ x, const float* __restrict__ Dv,
                            float* __restrict__ out) {
  const int r = blockIdx.x, c = threadIdx.x * 4;
  const size_t o = (size_t)r * DMODEL + c;
  short4 a0 = *(const short4*)(p + o);
  short4 a1 = *(const short4*)(p + (size_t)MROWS * DMODEL + o);
  float4 xv = *(const float4*)(x + o);
  float4 ov;
  ov.x = bf2f(a0.x) + bf2f(a1.x) + b_out[c + 0] + xv.x * Dv[c + 0];
  ov.y = bf2f(a0.y) + bf2f(a1.y) + b_out[c + 1] + xv.y * Dv[c + 1];
  ov.z = bf2f(a0.z) + bf2f(a1.z) + b_out[c + 2] + xv.z * Dv[c + 2];
  ov.w = bf2f(a0.w) + bf2f(a1.w) + b_out[c + 3] + xv.w * Dv[c + 3];
  *(float4*)(out + o) = ov;
}

// ---------------- chunked selective scan (2 phases) --------------------------
__global__ void scan_phase1(const float* __restrict__ md_sum, const float* __restrict__ A_log,
                            const float* __restrict__ bx,
                            float* __restrict__ chunk_prod, float* __restrict__ chunk_end) {
  const int n = threadIdx.x;                // 0..63 (state dim)
  const int c = blockIdx.x & (NCHUNK - 1);  // chunk
  const int b = blockIdx.x >> 6;            // batch
  const float An = -__expf(A_log[n]);
  float prod = 1.f, st = 0.f;
  const int t0 = c * LCHUNK;
#pragma unroll 4
  for (int i = 0; i < LCHUNK; ++i) {
    const int t = t0 + i;
    const float md = md_sum[b * SEQ + t] * (1.f / DMODEL);
    const float a = __expf(An * md);
    st = a * st + bx[((size_t)(b * SEQ + t)) * DSTATE + n];
    prod *= a;
  }
  chunk_prod[(b * NCHUNK + c) * DSTATE + n] = prod;
  chunk_end [(b * NCHUNK + c) * DSTATE + n] = st;
}

// phase3: redo own chunk-prefix, recompute a=exp(An*md), emit s_sum
__global__ void scan_phase3(const float* __restrict__ md_sum, const float* __restrict__ A_log,
                            const float* __restrict__ bx,
                            const float* __restrict__ chunk_prod,
                            const float* __restrict__ chunk_end,
                            float* __restrict__ s_sum) {
  const int n = threadIdx.x;
  const int c = blockIdx.x & (NCHUNK - 1);
  const int b = blockIdx.x >> 6;
  const float An = -__expf(A_log[n]);
  float st = 0.f;
  for (int cc = 0; cc < c; ++cc) {
    const size_t idx = ((size_t)(b * NCHUNK + cc)) * DSTATE + n;
    st = chunk_prod[idx] * st + chunk_end[idx];
  }
  const int t0 = c * LCHUNK;
#pragma unroll 4
  for (int i = 0; i < LCHUNK; ++i) {
    const int t = t0 + i;
    const float md = md_sum[b * SEQ + t] * (1.f / DMODEL);
    const float a = __expf(An * md);
    st = a * st + bx[((size_t)(b * SEQ + t)) * DSTATE + n];
    float v = st;
    v += __shfl_xor(v, 32); v += __shfl_xor(v, 16); v += __shfl_xor(v, 8);
    v += __shfl_xor(v, 4);  v += __shfl_xor(v, 2);  v += __shfl_xor(v, 1);
    if (n == 0) s_sum[b * SEQ + t] = v;
  }
}

// ---------------- y = s_sum * xi * g  (panel-staged in AND out, K=2048) ------
__global__ void ymul_kernel(const short* __restrict__ xi, const short* __restrict__ g,
                            const float* __restrict__ s_sum, short* __restrict__ y) {
  const int o = blockIdx.x * 256 + threadIdx.x;    // 16B group index, [0, 2M)
  const int row = ((o >> 12) << 4) | (o & 15);     // panel p = o>>12 (256 chunks)
  const size_t base = (size_t)o * 8;
  const float s = s_sum[row];
  short8 xv = *(const short8*)(xi + base);
  short8 gv = *(const short8*)(g + base);
  short8 yv;
#pragma unroll
  for (int k = 0; k < 8; ++k) yv[k] = f2bf(s * bf2f(xv[k]) * bf2f(gv[k]));
  *(short8*)(y + base) = yv;
}

// ---------------- launch ------------------------------------------------------
extern "C" void kernel_launch(void* const* d_in, const int* in_sizes, int n_in,
                              void* d_out, int out_size, void* d_ws, size_t ws_size,
                              hipStream_t stream) {
  const float* x     = (const float*)d_in[0];
  const float* W_in  = (const float*)d_in[1];
  const float* b_in  = (const float*)d_in[2];
  const float* W_xp  = (const float*)d_in[3];
  const float* b_xp  = (const float*)d_in[4];
  const float* W_dt  = (const float*)d_in[5];
  const float* b_dt  = (const float*)d_in[6];
  const float* W_out = (const float*)d_in[7];
  const float* b_out = (const float*)d_in[8];
  const float* A_log = (const float*)d_in[9];
  const float* Dv    = (const float*)d_in[10];

  char* ws = (char*)d_ws;
  size_t off = 0;
  auto alloc = [&](size_t bytes) -> void* {
    void* p = (void*)(ws + off);
    off += (bytes + 255) & ~(size_t)255;
    return p;
  };
  short* x_bf    = (short*)alloc((size_t)MROWS * DMODEL * 2);
  short* Wt_in   = (short*)alloc((size_t)4096 * 1024 * 2);
  short* Bcat    = (short*)alloc((size_t)NCAT * DINNER * 2);
  short* Wt_out  = (short*)alloc((size_t)1024 * 2048 * 2);
  short* xi      = (short*)alloc((size_t)MROWS * DINNER * 2);   // also G4 partials
  short* gbuf    = (short*)alloc((size_t)MROWS * DINNER * 2);
  short* ybuf    = (short*)alloc((size_t)MROWS * DINNER * 2);
  short* p2      = (short*)alloc((size_t)2 * MROWS * NCAT * 2); // G2 partials
  float* md_sum  = (float*)alloc((size_t)MROWS * 4);
  float* bx      = (float*)alloc((size_t)MROWS * DSTATE * 4);
  float* cprod   = (float*)alloc((size_t)2 * NCHUNK * DSTATE * 4);
  float* cend    = (float*)alloc((size_t)2 * NCHUNK * DSTATE * 4);
  float* s_sum   = (float*)alloc((size_t)MROWS * 4);

  // fused pre-pass: x->bf16 (panel-staged) + all 4 weight transposes
  prepass_kernel<<<PP4, 256, 0, stream>>>(x, x_bf, W_in, Wt_in, W_dt, W_xp, Bcat, W_out, Wt_out);

  // GEMM1: in_proj + silu split (panel-staged out); 256^2 read-ahead pipeline
  gemm256<0, 1024, 1024, 16, 1><<<512, 512, 0, stream>>>(x_bf, Wt_in, b_in, xi, gbuf);
  // GEMM2: split-K=2 partials + epilogue (softplus rowsum + bx); legacy 128^2
  gemm_bt<1, 2048, 1024, 9, 2><<<1152, 256, 0, stream>>>(xi, Bcat, nullptr, p2, nullptr);
  g2_epilogue<<<MROWS / 4, 256, 0, stream>>>(p2, b_dt, b_xp, md_sum, bx);
  // selective scan (phase3 self-computes its chunk prefix)
  scan_phase1<<<2 * NCHUNK, DSTATE, 0, stream>>>(md_sum, A_log, bx, cprod, cend);
  scan_phase3<<<2 * NCHUNK, DSTATE, 0, stream>>>(md_sum, A_log, bx, cprod, cend, s_sum);
  // y = s_sum * xi * g (panel-staged); xi dead afterwards
  ymul_kernel<<<MROWS * DINNER / 8 / 256, 256, 0, stream>>>(xi, gbuf, s_sum, ybuf);
  // GEMM4: split-K=2 partials into xi's slot + epilogue (+b_out + x*D); 256^2
  gemm256<1, 2048, 1024, 4, 2><<<256, 512, 0, stream>>>(ybuf, Wt_out, nullptr, xi, nullptr);
  g4_epilogue<<<MROWS, 256, 0, stream>>>(xi, b_out, x, Dv, (float*)d_out);
}

// Round 6
// 376.098 us; speedup vs baseline: 1.0356x; 1.0356x over previous
//
#include <hip/hip_runtime.h>

#define SEQ 4096
#define DMODEL 1024
#define DSTATE 64
#define DINNER 2048
#define MROWS 8192            // BATCH*SEQ
#define NCAT 1152             // Bcat rows: 1024 (dt) + 64 (xp) + 64 pad
#define NCHUNK 64             // scan chunks
#define LCHUNK 64             // steps per chunk

typedef __attribute__((ext_vector_type(8))) __bf16 bf16x8;
typedef __attribute__((ext_vector_type(8))) short short8;
typedef __attribute__((ext_vector_type(4))) float floatx4;

__device__ inline float bf2f(short s) {
  union { unsigned u; float f; } c;
  c.u = ((unsigned)(unsigned short)s) << 16;
  return c.f;
}
__device__ inline short f2bf(float f) {
  union { float f; unsigned u; } c; c.f = f;
  unsigned r = 0x7fffu + ((c.u >> 16) & 1u);
  return (short)((c.u + r) >> 16);
}
__device__ inline float silu_f(float v) {
  return v * __builtin_amdgcn_rcpf(1.f + __expf(-v));
}
__device__ inline float softplus_f(float v) {
  return fmaxf(v, 0.f) + log1pf(__expf(-fabsf(v)));
}
// async global->LDS, 16B per lane. LDS dest = wave-uniform base + lane*16.
__device__ inline void gld_lds16(const void* g, void* l) {
  __builtin_amdgcn_global_load_lds(
      (__attribute__((address_space(1))) void*)g,
      (__attribute__((address_space(3))) void*)l, 16, 0, 0);
}

// panel-staged bf16 layout: panel = 16 rows, stored contiguously (K*32 bytes),
// inside: [k-chunk of 8][row-in-panel 16][8 elems].  element (r,k):
__device__ inline size_t permOff(int r, int k, int K) {
  return (((size_t)(r >> 4) * (K >> 3) + (k >> 3)) << 7) + ((r & 15) << 3) + (k & 7);
}

// ---------------- fused pre-pass ---------------------------------------------
#define PP0 4096
#define PP1 (PP0 + 4096)
#define PP2 (PP1 + 2048)
#define PP3 (PP2 + 128)
#define PP4 (PP3 + 2048)

__device__ void tile_transpose_perm(const float* __restrict__ in, short* __restrict__ out,
                                    int R, int C, int bx, int by, float (*tile)[33]) {
  const int tx = threadIdx.x & 31, ty = threadIdx.x >> 5;   // 32 x 8
  const int cb = bx * 32, rb = by * 32;
#pragma unroll
  for (int i = 0; i < 32; i += 8) {
    int r = rb + ty + i, c = cb + tx;
    tile[ty + i][tx] = (r < R && c < C) ? in[(size_t)r * C + c] : 0.f;
  }
  __syncthreads();
#pragma unroll
  for (int i = 0; i < 32; i += 8) {
    int orow = cb + ty + i, oc = rb + tx;   // out(row=orow, k=oc) = in[oc][orow]
    if (orow < C && oc < R) out[permOff(orow, oc, R)] = f2bf(tile[tx][ty + i]);
  }
}

__global__ void prepass_kernel(const float* __restrict__ x, short* __restrict__ x_bf,
                               const float* __restrict__ W_in, short* __restrict__ Wt_in,
                               const float* __restrict__ W_dt, const float* __restrict__ W_xp,
                               short* __restrict__ Bcat,
                               const float* __restrict__ W_out, short* __restrict__ Wt_out) {
  __shared__ float tile[32][33];
  const int blk = blockIdx.x;
  if (blk < PP0) {
    int o = blk * 256 + threadIdx.x;            // [0, 1M) 16B groups
    int m = o & 15, rest = o >> 4;
    int c = rest & 127, p = rest >> 7;          // K/8 = 128 chunks
    const float* src = x + ((size_t)(p * 16 + m)) * 1024 + c * 8;
    float4 v0 = ((const float4*)src)[0];
    float4 v1 = ((const float4*)src)[1];
    short8 ov;
    ov[0] = f2bf(v0.x); ov[1] = f2bf(v0.y); ov[2] = f2bf(v0.z); ov[3] = f2bf(v0.w);
    ov[4] = f2bf(v1.x); ov[5] = f2bf(v1.y); ov[6] = f2bf(v1.z); ov[7] = f2bf(v1.w);
    ((short8*)x_bf)[o] = ov;
  } else if (blk < PP1) {
    int t = blk - PP0;
    tile_transpose_perm(W_in, Wt_in, 1024, 4096, t & 127, t >> 7, tile);
  } else if (blk < PP2) {
    int t = blk - PP1;
    tile_transpose_perm(W_dt, Bcat, 2048, 1024, t & 31, t >> 5, tile);
  } else if (blk < PP3) {
    int t = blk - PP2;
    tile_transpose_perm(W_xp, Bcat + (size_t)1024 * DINNER, 2048, 64, t & 1, t >> 1, tile);
  } else {
    int t = blk - PP3;
    tile_transpose_perm(W_out, Wt_out, 2048, 1024, t & 31, t >> 5, tile);
  }
}

// ---------------- 256x256 read-ahead bf16 GEMM (counted-lgkm pipeline) -------
// R5-verified schedule (80.4us/36% on GEMM1). 512 thr = 8 waves (2M x 4N);
// wave owns 128x64 = 8x4 frags. BK=64, 2 LDS buffers x 64KB = 128KB.
// Read group for MFMA cluster k+1 issued BEFORE cluster k's MFMAs -> compiler
// emits counted lgkmcnt; LDS port overlaps matrix pipe. Two barriers/tile
// (B_A before G0 reads, B_B before G2 reads), counted vmcnt(4) twice/tile.
// Ledger: phD(t-1) stage Q(t,3) -> outstanding Q(t,0..3)=8 -> vmcnt(4)
// retires Q(t,0),Q(t,1). phB(t) stage Q(t+1,1) -> vmcnt(4) retires
// Q(t,2),Q(t,3). WAR: lgkmcnt(0) precedes each barrier. Never drains mid-loop.
template <int MODE, int KTOT, int KSL, int NT, int ZS>
__global__ __launch_bounds__(512, 2) void gemm256(
    const short* __restrict__ A, const short* __restrict__ Bt,
    const float* __restrict__ bias,
    void* __restrict__ out0, void* __restrict__ out1)
{
  __shared__ __attribute__((aligned(16))) short sLds[65536];   // 128 KiB

  const int tid = threadIdx.x;
  const int lane = tid & 63;
  const int w = tid >> 6;              // 0..7
  const int wr = w >> 2, wc = w & 3;   // 2 x 4 wave grid
  const int m = lane & 15, quad = lane >> 4;

  // XCD-aware 1D grid: each XCD owns a 4-M-tile stripe (A stays in its L2).
  const int xcd = blockIdx.x & 7;
  const int q = blockIdx.x >> 3;
  const int mt = xcd * 4 + (q & 3);
  const int rest = q >> 2;
  const int ntile = rest % NT;
  const int z = rest / NT;
  const int bM = mt * 256, bN = ntile * 256;
  const int kbeg = z * KSL;

  floatx4 acc[8][4] = {};

  const size_t PS = (size_t)KTOT * 16;   // panel stride in shorts
  const short* AgA = A  + ((size_t)(bM >> 4) + w) * PS + (size_t)kbeg * 16 + lane * 8;
  const short* AgB = AgA + 8 * PS;
  const short* BgA = Bt + ((size_t)(bN >> 4) + w) * PS + (size_t)kbeg * 16 + lane * 8;
  const short* BgB = BgA + 8 * PS;

  constexpr int KT = KSL / 64;           // K-tiles of 64 (>= 2)

  // LDS map (shorts): buf(t&1)*32768 + {A:0, B:16384} + kh*8192 + panel*512
  auto STAGE_Q = [&](int t, int qq) {    // quarter qq: 0:A-kh0 1:B-kh0 2:A-kh1 3:B-kh1
    const size_t go = (size_t)t * 1024 + (size_t)(qq >> 1) * 512;
    short* d = sLds + ((t & 1) << 15) + ((qq & 1) << 14) + ((qq >> 1) << 13) + w * 512;
    const short* g0 = (qq & 1) ? BgA : AgA;   // panel w
    const short* g1 = (qq & 1) ? BgB : AgB;   // panel w+8
    gld_lds16(g0 + go, d);
    gld_lds16(g1 + go, d + 4096);
  };

  const int aoff = wr * 4096 + quad * 128 + m * 8;           // + rt*512 + kh*8192
  const int boff = 16384 + wc * 2048 + quad * 128 + m * 8;   // + ct*512 + kh*8192

  bf16x8 aA[4], aB[4], bA[4], bB[4];

  // prologue: tile 0 fully staged; kh0 half waited; G0(0) issued
  STAGE_Q(0, 0); STAGE_Q(0, 1); STAGE_Q(0, 2); STAGE_Q(0, 3);
  asm volatile("s_waitcnt vmcnt(4)" ::: "memory");   // Q(0,0),Q(0,1) landed (mine)
  asm volatile("s_barrier" ::: "memory");            // B_A(0)
  {
    const short* bs = sLds;
#pragma unroll
    for (int rt = 0; rt < 4; ++rt) aA[rt] = *(const bf16x8*)(bs + aoff + rt * 512);
#pragma unroll
    for (int ct = 0; ct < 4; ++ct) bA[ct] = *(const bf16x8*)(bs + boff + ct * 512);
    if (KT > 1) STAGE_Q(1, 0);
    __builtin_amdgcn_sched_barrier(0);
  }

#pragma unroll 1
  for (int t = 0; t < KT; ++t) {
    const short* bs = sLds + ((t & 1) << 15);
    const bool pf = (t + 1 < KT);

    // ---- phase B: issue G1(t) | stage Q(t+1,1) | vmcnt | M0 (G0 ops, counted lgkm)
#pragma unroll
    for (int rt = 0; rt < 4; ++rt) aB[rt] = *(const bf16x8*)(bs + aoff + (4 + rt) * 512);
    if (pf) {
      STAGE_Q(t + 1, 1);
      asm volatile("s_waitcnt vmcnt(4)" ::: "memory");   // Q(t,2),Q(t,3) landed
    } else {
      asm volatile("s_waitcnt vmcnt(0)" ::: "memory");   // tail: last 4 stages
    }
    __builtin_amdgcn_sched_barrier(0);
    __builtin_amdgcn_s_setprio(1);
#pragma unroll
    for (int rt = 0; rt < 4; ++rt)
#pragma unroll
      for (int ct = 0; ct < 4; ++ct)
        acc[rt][ct] = __builtin_amdgcn_mfma_f32_16x16x32_bf16(aA[rt], bA[ct], acc[rt][ct], 0, 0, 0);
    __builtin_amdgcn_s_setprio(0);
    __builtin_amdgcn_sched_barrier(0);

    // ---- phase C: lgkm0+B_B(t) | issue G2(t) | stage Q(t+1,2) | M1 (G1+bA)
    asm volatile("s_waitcnt lgkmcnt(0)" ::: "memory");   // G1 retired (all reads done)
    asm volatile("s_barrier" ::: "memory");              // B_B(t): kh1 landed globally
#pragma unroll
    for (int rt = 0; rt < 4; ++rt) aA[rt] = *(const bf16x8*)(bs + 8192 + aoff + rt * 512);
#pragma unroll
    for (int ct = 0; ct < 4; ++ct) bB[ct] = *(const bf16x8*)(bs + 8192 + boff + ct * 512);
    if (pf) STAGE_Q(t + 1, 2);
    __builtin_amdgcn_sched_barrier(0);
    __builtin_amdgcn_s_setprio(1);
#pragma unroll
    for (int rt = 0; rt < 4; ++rt)
#pragma unroll
      for (int ct = 0; ct < 4; ++ct)
        acc[4 + rt][ct] = __builtin_amdgcn_mfma_f32_16x16x32_bf16(aB[rt], bA[ct], acc[4 + rt][ct], 0, 0, 0);
    __builtin_amdgcn_s_setprio(0);
    __builtin_amdgcn_sched_barrier(0);

    // ---- phase D: issue G3(t) | stage Q(t+1,3) | vmcnt | M2 (G2 ops, counted lgkm)
#pragma unroll
    for (int rt = 0; rt < 4; ++rt) aB[rt] = *(const bf16x8*)(bs + 8192 + aoff + (4 + rt) * 512);
    if (pf) {
      STAGE_Q(t + 1, 3);
      asm volatile("s_waitcnt vmcnt(4)" ::: "memory");   // Q(t+1,0),Q(t+1,1) landed
    }
    __builtin_amdgcn_sched_barrier(0);
    __builtin_amdgcn_s_setprio(1);
#pragma unroll
    for (int rt = 0; rt < 4; ++rt)
#pragma unroll
      for (int ct = 0; ct < 4; ++ct)
        acc[rt][ct] = __builtin_amdgcn_mfma_f32_16x16x32_bf16(aA[rt], bB[ct], acc[rt][ct], 0, 0, 0);
    __builtin_amdgcn_s_setprio(0);
    __builtin_amdgcn_sched_barrier(0);

    // ---- phase A(t+1): lgkm0+B_A | issue G0(t+1) | stage Q(t+2,0)
    if (pf) {
      asm volatile("s_waitcnt lgkmcnt(0)" ::: "memory"); // G3 retired: WAR-safe
      asm volatile("s_barrier" ::: "memory");            // B_A(t+1)
      const short* bs2 = sLds + (((t + 1) & 1) << 15);
#pragma unroll
      for (int rt = 0; rt < 4; ++rt) aA[rt] = *(const bf16x8*)(bs2 + aoff + rt * 512);
#pragma unroll
      for (int ct = 0; ct < 4; ++ct) bA[ct] = *(const bf16x8*)(bs2 + boff + ct * 512);
      if (t + 2 < KT) STAGE_Q(t + 2, 0);
      __builtin_amdgcn_sched_barrier(0);
    }
    // ---- M3(t): G3 x G2's B (operands already retired or auto-waited)
    __builtin_amdgcn_s_setprio(1);
#pragma unroll
    for (int rt = 0; rt < 4; ++rt)
#pragma unroll
      for (int ct = 0; ct < 4; ++ct)
        acc[4 + rt][ct] = __builtin_amdgcn_mfma_f32_16x16x32_bf16(aB[rt], bB[ct], acc[4 + rt][ct], 0, 0, 0);
    __builtin_amdgcn_s_setprio(0);
    __builtin_amdgcn_sched_barrier(0);
  }

  const int rowbase = bM + wr * 128;
  const int colbase = bN + wc * 64;

  if constexpr (MODE == 0) {
    // silu epilogue, panel-staged out; 256-wide tiles never straddle DINNER.
    short* dst = (bN < DINNER) ? (short*)out0 : (short*)out1;
    const int cb = (bN < DINNER) ? colbase : colbase - DINNER;
#pragma unroll
    for (int rt = 0; rt < 8; ++rt) {
      const size_t rowPan = ((size_t)(rowbase >> 4) + rt) << 8;   // *256 chunks
#pragma unroll
      for (int ct = 0; ct < 4; ++ct) {
        const int colA = colbase + ct * 16 + m;
        const int colP = cb + ct * 16 + m;
        const size_t base = ((rowPan + (colP >> 3)) << 7) + (colP & 7) + ((size_t)quad * 32);
        const float bv = bias[colA];
#pragma unroll
        for (int reg = 0; reg < 4; ++reg) {
          float val = acc[rt][ct][reg] + bv;
          dst[base + reg * 8] = f2bf(silu_f(val));
        }
      }
    }
  } else {
    // raw bf16 partials, row-major stride N, +z slice offset
    constexpr int N = NT * 256;
    short* dst = (short*)out0 + (size_t)z * MROWS * N;
#pragma unroll
    for (int rt = 0; rt < 8; ++rt)
#pragma unroll
      for (int ct = 0; ct < 4; ++ct) {
        const int col = colbase + ct * 16 + m;
#pragma unroll
        for (int reg = 0; reg < 4; ++reg) {
          const int r = rowbase + rt * 16 + quad * 4 + reg;
          dst[(size_t)r * N + col] = f2bf(acc[rt][ct][reg]);
        }
      }
  }
}

// ---------------- skinny xp GEMM: bx partials = xi @ W_xp (fp32) -------------
// N=64, K=2048 split-K=2 -> 256 blocks x 256 thr (4 waves). Block = 64 rows
// (4 A-panels, one per wave) x 64 cols (4 B-panels, shared). Double-buffered
// LDS (2 x 16KB), 1-ahead prefetch, counted vmcnt(4). Writes fully-parallel
// fp32 partials bxp[z][8192][64]; scans add the two slices + b_xp.
__global__ __launch_bounds__(256) void xp_gemm(const short* __restrict__ xi,
                                               const short* __restrict__ Bxp,
                                               float* __restrict__ bxp) {
  __shared__ __attribute__((aligned(16))) short sA[2][4096];
  __shared__ __attribute__((aligned(16))) short sB[2][4096];
  const int tid = threadIdx.x, lane = tid & 63, w = tid >> 6;
  const int m = lane & 15, quad = lane >> 4;
  const int z = blockIdx.x >> 7;            // K-slice
  const int rb = (blockIdx.x & 127) * 64;   // row base
  const size_t PS = (size_t)2048 * 16;      // panel stride (shorts)
  const short* Ag = xi  + ((size_t)(rb >> 4) + w) * PS + (size_t)z * 1024 * 16 + lane * 8;
  const short* Bg = Bxp + (size_t)w * PS + (size_t)z * 1024 * 16 + lane * 8;
  floatx4 acc[4] = {};
  auto STAGE = [&](int t) {                 // 4 gld_lds per wave
    const size_t go = (size_t)t * 1024;     // 64 k -> 1024 shorts per panel
    short* da = sA[t & 1] + w * 1024;
    short* db = sB[t & 1] + w * 1024;
    gld_lds16(Ag + go, da); gld_lds16(Ag + go + 512, da + 512);
    gld_lds16(Bg + go, db); gld_lds16(Bg + go + 512, db + 512);
  };
  STAGE(0);
#pragma unroll 1
  for (int t = 0; t < 16; ++t) {
    __builtin_amdgcn_s_barrier();          // all reads of buf (t+1)&1 retired
    if (t + 1 < 16) {
      STAGE(t + 1);                         // outstanding: tile t (4) + t+1 (4)
      asm volatile("s_waitcnt vmcnt(4)" ::: "memory");   // tile t landed
    } else {
      asm volatile("s_waitcnt vmcnt(0)" ::: "memory");
    }
    __builtin_amdgcn_s_barrier();          // tile t visible to all waves
    const short* a0 = sA[t & 1] + w * 1024 + quad * 128 + m * 8;
    const short* b0 = sB[t & 1] + quad * 128 + m * 8;
#pragma unroll
    for (int kh = 0; kh < 2; ++kh) {
      bf16x8 a = *(const bf16x8*)(a0 + kh * 512);
#pragma unroll
      for (int ct = 0; ct < 4; ++ct) {
        bf16x8 b = *(const bf16x8*)(b0 + ct * 1024 + kh * 512);
        acc[ct] = __builtin_amdgcn_mfma_f32_16x16x32_bf16(a, b, acc[ct], 0, 0, 0);
      }
    }
  }
  float* dst = bxp + (size_t)z * MROWS * DSTATE;
#pragma unroll
  for (int ct = 0; ct < 4; ++ct)
#pragma unroll
    for (int reg = 0; reg < 4; ++reg)
      dst[(size_t)(rb + w * 16 + quad * 4 + reg) * DSTATE + ct * 16 + m] = acc[ct][reg];
}

// ---------------- split-K combine epilogues ----------------------------------
// G2: one wave per row; p[2][8192][1024] bf16 dt-partials -> md_sum
__global__ void g2_epilogue(const short* __restrict__ p, const float* __restrict__ b_dt,
                            float* __restrict__ md_sum) {
  const int row = blockIdx.x * 4 + (threadIdx.x >> 6);
  const int lane = threadIdx.x & 63;
  const size_t base0 = (size_t)row * 1024;
  const size_t base1 = base0 + (size_t)MROWS * 1024;
  short8 a0 = *(const short8*)(p + base0 + lane * 16);
  short8 a1 = *(const short8*)(p + base0 + lane * 16 + 8);
  short8 c0 = *(const short8*)(p + base1 + lane * 16);
  short8 c1 = *(const short8*)(p + base1 + lane * 16 + 8);
  float s = 0.f;
#pragma unroll
  for (int j = 0; j < 8; ++j) {
    s += softplus_f(bf2f(a0[j]) + bf2f(c0[j]) + b_dt[lane * 16 + j]);
    s += softplus_f(bf2f(a1[j]) + bf2f(c1[j]) + b_dt[lane * 16 + 8 + j]);
  }
  s += __shfl_xor(s, 1);  s += __shfl_xor(s, 2);  s += __shfl_xor(s, 4);
  s += __shfl_xor(s, 8);  s += __shfl_xor(s, 16); s += __shfl_xor(s, 32);
  if (lane == 0) md_sum[row] = s;
}

// G4: out = p0 + p1 + b_out + x*D   (fp32 row-major [8192,1024])
__global__ void g4_epilogue(const short* __restrict__ p, const float* __restrict__ b_out,
                            const float* __restrict__ x, const float* __restrict__ Dv,
                            float* __restrict__ out) {
  const int r = blockIdx.x, c = threadIdx.x * 4;
  const size_t o = (size_t)r * DMODEL + c;
  short4 a0 = *(const short4*)(p + o);
  short4 a1 = *(const short4*)(p + (size_t)MROWS * DMODEL + o);
  float4 xv = *(const float4*)(x + o);
  float4 ov;
  ov.x = bf2f(a0.x) + bf2f(a1.x) + b_out[c + 0] + xv.x * Dv[c + 0];
  ov.y = bf2f(a0.y) + bf2f(a1.y) + b_out[c + 1] + xv.y * Dv[c + 1];
  ov.z = bf2f(a0.z) + bf2f(a1.z) + b_out[c + 2] + xv.z * Dv[c + 2];
  ov.w = bf2f(a0.w) + bf2f(a1.w) + b_out[c + 3] + xv.w * Dv[c + 3];
  *(float4*)(out + o) = ov;
}

// ---------------- chunked selective scan (2 phases) --------------------------
// bx value = bxp[0][row][n] + bxp[1][row][n] + b_xp[n] (fp32 split-K partials)
__global__ void scan_phase1(const float* __restrict__ md_sum, const float* __restrict__ A_log,
                            const float* __restrict__ bxp, const float* __restrict__ b_xp,
                            float* __restrict__ chunk_prod, float* __restrict__ chunk_end) {
  const int n = threadIdx.x;                // 0..63 (state dim)
  const int c = blockIdx.x & (NCHUNK - 1);  // chunk
  const int b = blockIdx.x >> 6;            // batch
  const float An = -__expf(A_log[n]);
  const float bxn = b_xp[n];
  const float* bx0 = bxp;
  const float* bx1 = bxp + (size_t)MROWS * DSTATE;
  float prod = 1.f, st = 0.f;
  const int t0 = c * LCHUNK;
#pragma unroll 4
  for (int i = 0; i < LCHUNK; ++i) {
    const int t = t0 + i;
    const float md = md_sum[b * SEQ + t] * (1.f / DMODEL);
    const float a = __expf(An * md);
    const size_t idx = ((size_t)(b * SEQ + t)) * DSTATE + n;
    st = a * st + (bx0[idx] + bx1[idx] + bxn);
    prod *= a;
  }
  chunk_prod[(b * NCHUNK + c) * DSTATE + n] = prod;
  chunk_end [(b * NCHUNK + c) * DSTATE + n] = st;
}

// phase3: redo own chunk-prefix, recompute a=exp(An*md), emit s_sum
__global__ void scan_phase3(const float* __restrict__ md_sum, const float* __restrict__ A_log,
                            const float* __restrict__ bxp, const float* __restrict__ b_xp,
                            const float* __restrict__ chunk_prod,
                            const float* __restrict__ chunk_end,
                            float* __restrict__ s_sum) {
  const int n = threadIdx.x;
  const int c = blockIdx.x & (NCHUNK - 1);
  const int b = blockIdx.x >> 6;
  const float An = -__expf(A_log[n]);
  const float bxn = b_xp[n];
  const float* bx0 = bxp;
  const float* bx1 = bxp + (size_t)MROWS * DSTATE;
  float st = 0.f;
#pragma unroll 4
  for (int cc = 0; cc < c; ++cc) {
    const size_t idx = ((size_t)(b * NCHUNK + cc)) * DSTATE + n;
    st = chunk_prod[idx] * st + chunk_end[idx];
  }
  const int t0 = c * LCHUNK;
#pragma unroll 4
  for (int i = 0; i < LCHUNK; ++i) {
    const int t = t0 + i;
    const float md = md_sum[b * SEQ + t] * (1.f / DMODEL);
    const float a = __expf(An * md);
    const size_t idx = ((size_t)(b * SEQ + t)) * DSTATE + n;
    st = a * st + (bx0[idx] + bx1[idx] + bxn);
    float v = st;
    v += __shfl_xor(v, 32); v += __shfl_xor(v, 16); v += __shfl_xor(v, 8);
    v += __shfl_xor(v, 4);  v += __shfl_xor(v, 2);  v += __shfl_xor(v, 1);
    if (n == 0) s_sum[b * SEQ + t] = v;
  }
}

// ---------------- y = s_sum * xi * g  (panel-staged in AND out, K=2048) ------
__global__ void ymul_kernel(const short* __restrict__ xi, const short* __restrict__ g,
                            const float* __restrict__ s_sum, short* __restrict__ y) {
  const int o = blockIdx.x * 256 + threadIdx.x;    // 16B group index, [0, 2M)
  const int row = ((o >> 12) << 4) | (o & 15);     // panel p = o>>12 (256 chunks)
  const size_t base = (size_t)o * 8;
  const float s = s_sum[row];
  short8 xv = *(const short8*)(xi + base);
  short8 gv = *(const short8*)(g + base);
  short8 yv;
#pragma unroll
  for (int k = 0; k < 8; ++k) yv[k] = f2bf(s * bf2f(xv[k]) * bf2f(gv[k]));
  *(short8*)(y + base) = yv;
}

// ---------------- launch ------------------------------------------------------
extern "C" void kernel_launch(void* const* d_in, const int* in_sizes, int n_in,
                              void* d_out, int out_size, void* d_ws, size_t ws_size,
                              hipStream_t stream) {
  const float* x     = (const float*)d_in[0];
  const float* W_in  = (const float*)d_in[1];
  const float* b_in  = (const float*)d_in[2];
  const float* W_xp  = (const float*)d_in[3];
  const float* b_xp  = (const float*)d_in[4];
  const float* W_dt  = (const float*)d_in[5];
  const float* b_dt  = (const float*)d_in[6];
  const float* W_out = (const float*)d_in[7];
  const float* b_out = (const float*)d_in[8];
  const float* A_log = (const float*)d_in[9];
  const float* Dv    = (const float*)d_in[10];

  char* ws = (char*)d_ws;
  size_t off = 0;
  auto alloc = [&](size_t bytes) -> void* {
    void* p = (void*)(ws + off);
    off += (bytes + 255) & ~(size_t)255;
    return p;
  };
  short* x_bf    = (short*)alloc((size_t)MROWS * DMODEL * 2);
  short* Wt_in   = (short*)alloc((size_t)4096 * 1024 * 2);
  short* Bcat    = (short*)alloc((size_t)NCAT * DINNER * 2);
  short* Wt_out  = (short*)alloc((size_t)1024 * 2048 * 2);
  short* xi      = (short*)alloc((size_t)MROWS * DINNER * 2);   // also G4 partials
  short* gbuf    = (short*)alloc((size_t)MROWS * DINNER * 2);
  short* ybuf    = (short*)alloc((size_t)MROWS * DINNER * 2);
  short* p2      = (short*)alloc((size_t)2 * MROWS * 1024 * 2); // G2 dt partials
  float* md_sum  = (float*)alloc((size_t)MROWS * 4);
  float* bxp     = (float*)alloc((size_t)2 * MROWS * DSTATE * 4); // xp partials
  float* cprod   = (float*)alloc((size_t)2 * NCHUNK * DSTATE * 4);
  float* cend    = (float*)alloc((size_t)2 * NCHUNK * DSTATE * 4);
  float* s_sum   = (float*)alloc((size_t)MROWS * 4);

  // fused pre-pass: x->bf16 (panel-staged) + all 4 weight transposes
  prepass_kernel<<<PP4, 256, 0, stream>>>(x, x_bf, W_in, Wt_in, W_dt, W_xp, Bcat, W_out, Wt_out);

  // GEMM1: in_proj + silu split (panel-staged out); 256^2 read-ahead pipeline
  gemm256<0, 1024, 1024, 16, 1><<<512, 512, 0, stream>>>(x_bf, Wt_in, b_in, xi, gbuf);
  // GEMM2-dt: 256^2 pipeline, split-K=2, N=1024 -> one clean round (256 blocks)
  gemm256<1, 2048, 1024, 4, 2><<<256, 512, 0, stream>>>(xi, Bcat, nullptr, p2, nullptr);
  // GEMM2-xp: skinny N=64, fp32 partials straight into bxp
  xp_gemm<<<256, 256, 0, stream>>>(xi, Bcat + (size_t)1024 * DINNER, bxp);
  // combine dt partials -> softplus rowsum
  g2_epilogue<<<MROWS / 4, 256, 0, stream>>>(p2, b_dt, md_sum);
  // selective scan (phase3 self-computes its chunk prefix)
  scan_phase1<<<2 * NCHUNK, DSTATE, 0, stream>>>(md_sum, A_log, bxp, b_xp, cprod, cend);
  scan_phase3<<<2 * NCHUNK, DSTATE, 0, stream>>>(md_sum, A_log, bxp, b_xp, cprod, cend, s_sum);
  // y = s_sum * xi * g (panel-staged); xi dead afterwards
  ymul_kernel<<<MROWS * DINNER / 8 / 256, 256, 0, stream>>>(xi, gbuf, s_sum, ybuf);
  // GEMM4: split-K=2 partials into xi's slot + epilogue (+b_out + x*D); 256^2
  gemm256<1, 2048, 1024, 4, 2><<<256, 512, 0, stream>>>(ybuf, Wt_out, nullptr, xi, nullptr);
  g4_epilogue<<<MROWS, 256, 0, stream>>>(xi, b_out, x, Dv, (float*)d_out);
}

// Round 7
// 354.510 us; speedup vs baseline: 1.0986x; 1.0609x over previous
//
#include <hip/hip_runtime.h>

#define SEQ 4096
#define DMODEL 1024
#define DSTATE 64
#define DINNER 2048
#define MROWS 8192            // BATCH*SEQ
#define NCAT 1152             // Bcat rows: 1024 (dt) + 64 (xp) + 64 pad
#define NCHUNK 64             // scan chunks
#define LCHUNK 64             // steps per chunk

typedef __attribute__((ext_vector_type(8))) __bf16 bf16x8;
typedef __attribute__((ext_vector_type(8))) short short8;
typedef __attribute__((ext_vector_type(4))) float floatx4;

__device__ inline float bf2f(short s) {
  union { unsigned u; float f; } c;
  c.u = ((unsigned)(unsigned short)s) << 16;
  return c.f;
}
__device__ inline short f2bf(float f) {
  union { float f; unsigned u; } c; c.f = f;
  unsigned r = 0x7fffu + ((c.u >> 16) & 1u);
  return (short)((c.u + r) >> 16);
}
__device__ inline float silu_f(float v) {
  return v * __builtin_amdgcn_rcpf(1.f + __expf(-v));
}
__device__ inline float softplus_f(float v) {
  return fmaxf(v, 0.f) + log1pf(__expf(-fabsf(v)));
}
// async global->LDS, 16B per lane. LDS dest = wave-uniform base + lane*16.
__device__ inline void gld_lds16(const void* g, void* l) {
  __builtin_amdgcn_global_load_lds(
      (__attribute__((address_space(1))) void*)g,
      (__attribute__((address_space(3))) void*)l, 16, 0, 0);
}

// panel-staged bf16 layout: panel = 16 rows, stored contiguously (K*32 bytes),
// inside: [k-chunk of 8][row-in-panel 16][8 elems].  element (r,k):
__device__ inline size_t permOff(int r, int k, int K) {
  return (((size_t)(r >> 4) * (K >> 3) + (k >> 3)) << 7) + ((r & 15) << 3) + (k & 7);
}

// in_proj column pairing: xi col c -> newrow ((c>>4)<<5)|(c&15);
// g col c (orig 2048+c) -> newrow ((c>>4)<<5)|16|(c&15). Each 32-row block of
// Wt_in = 16 xi cols + their 16 matching g cols -> GEMM1 fragment pair
// (ct even, ct odd) holds xi and g for the SAME phi in the SAME lane.
__device__ inline int inproj_remap(int oc) {
  const int c = (oc < DINNER) ? oc : oc - DINNER;
  return ((c >> 4) << 5) | ((oc < DINNER) ? 0 : 16) | (c & 15);
}

// ---------------- fused pre-pass ---------------------------------------------
#define PP0 4096
#define PP1 (PP0 + 4096)
#define PP2 (PP1 + 2048)
#define PP3 (PP2 + 128)
#define PP4 (PP3 + 2048)

__device__ void tile_transpose_perm(const float* __restrict__ in, short* __restrict__ out,
                                    int R, int C, int bx, int by, float (*tile)[33],
                                    int remap) {
  const int tx = threadIdx.x & 31, ty = threadIdx.x >> 5;   // 32 x 8
  const int cb = bx * 32, rb = by * 32;
#pragma unroll
  for (int i = 0; i < 32; i += 8) {
    int r = rb + ty + i, c = cb + tx;
    tile[ty + i][tx] = (r < R && c < C) ? in[(size_t)r * C + c] : 0.f;
  }
  __syncthreads();
#pragma unroll
  for (int i = 0; i < 32; i += 8) {
    int orow = cb + ty + i, oc = rb + tx;   // out(row=orow, k=oc) = in[oc][orow]
    if (orow < C && oc < R) {
      int nr = remap ? inproj_remap(orow) : orow;
      out[permOff(nr, oc, R)] = f2bf(tile[tx][ty + i]);
    }
  }
}

__global__ void prepass_kernel(const float* __restrict__ x, short* __restrict__ x_bf,
                               const float* __restrict__ W_in, short* __restrict__ Wt_in,
                               const float* __restrict__ W_dt, const float* __restrict__ W_xp,
                               short* __restrict__ Bcat,
                               const float* __restrict__ W_out, short* __restrict__ Wt_out) {
  __shared__ float tile[32][33];
  const int blk = blockIdx.x;
  if (blk < PP0) {
    int o = blk * 256 + threadIdx.x;            // [0, 1M) 16B groups
    int m = o & 15, rest = o >> 4;
    int c = rest & 127, p = rest >> 7;          // K/8 = 128 chunks
    const float* src = x + ((size_t)(p * 16 + m)) * 1024 + c * 8;
    float4 v0 = ((const float4*)src)[0];
    float4 v1 = ((const float4*)src)[1];
    short8 ov;
    ov[0] = f2bf(v0.x); ov[1] = f2bf(v0.y); ov[2] = f2bf(v0.z); ov[3] = f2bf(v0.w);
    ov[4] = f2bf(v1.x); ov[5] = f2bf(v1.y); ov[6] = f2bf(v1.z); ov[7] = f2bf(v1.w);
    ((short8*)x_bf)[o] = ov;
  } else if (blk < PP1) {
    int t = blk - PP0;
    tile_transpose_perm(W_in, Wt_in, 1024, 4096, t & 127, t >> 7, tile, 1);
  } else if (blk < PP2) {
    int t = blk - PP1;
    tile_transpose_perm(W_dt, Bcat, 2048, 1024, t & 31, t >> 5, tile, 0);
  } else if (blk < PP3) {
    int t = blk - PP2;
    tile_transpose_perm(W_xp, Bcat + (size_t)1024 * DINNER, 2048, 64, t & 1, t >> 1, tile, 0);
  } else {
    int t = blk - PP3;
    tile_transpose_perm(W_out, Wt_out, 2048, 1024, t & 31, t >> 5, tile, 0);
  }
}

// ---------------- 256x256 read-ahead bf16 GEMM (counted-lgkm pipeline) -------
// R5-verified schedule (80.4us/36% on GEMM1). 512 thr = 8 waves (2M x 4N);
// wave owns 128x64 = 8x4 frags. BK=64, 2 LDS buffers x 64KB = 128KB.
// Read group for MFMA cluster k+1 issued BEFORE cluster k's MFMAs -> compiler
// emits counted lgkmcnt; LDS port overlaps matrix pipe. Two barriers/tile
// (B_A before G0 reads, B_B before G2 reads), counted vmcnt(4) twice/tile.
// Ledger: phD(t-1) stage Q(t,3) -> outstanding Q(t,0..3)=8 -> vmcnt(4)
// retires Q(t,0),Q(t,1). phB(t) stage Q(t+1,1) -> vmcnt(4) retires
// Q(t,2),Q(t,3). WAR: lgkmcnt(0) precedes each barrier. Never drains mid-loop.
// MODE 0: paired in_proj epilogue (remapped Wt_in): even ct frag = xi col phi,
//   odd ct frag = g col phi (same lane). Writes xi=silu(.) to out0 and
//   prod=silu(xi)*silu(g) to out1 (panel-staged, 2048-wide each). The s_sum
//   scale is applied later in g4_epilogue (linearity of matmul in A-rows).
// MODE 1: raw bf16 split-K partials, row-major stride N.
template <int MODE, int KTOT, int KSL, int NT, int ZS>
__global__ __launch_bounds__(512, 2) void gemm256(
    const short* __restrict__ A, const short* __restrict__ Bt,
    const float* __restrict__ bias,
    void* __restrict__ out0, void* __restrict__ out1)
{
  __shared__ __attribute__((aligned(16))) short sLds[65536];   // 128 KiB

  const int tid = threadIdx.x;
  const int lane = tid & 63;
  const int w = tid >> 6;              // 0..7
  const int wr = w >> 2, wc = w & 3;   // 2 x 4 wave grid
  const int m = lane & 15, quad = lane >> 4;

  // XCD-aware 1D grid: each XCD owns a 4-M-tile stripe (A stays in its L2).
  const int xcd = blockIdx.x & 7;
  const int q = blockIdx.x >> 3;
  const int mt = xcd * 4 + (q & 3);
  const int rest = q >> 2;
  const int ntile = rest % NT;
  const int z = rest / NT;
  const int bM = mt * 256, bN = ntile * 256;
  const int kbeg = z * KSL;

  floatx4 acc[8][4] = {};

  const size_t PS = (size_t)KTOT * 16;   // panel stride in shorts
  const short* AgA = A  + ((size_t)(bM >> 4) + w) * PS + (size_t)kbeg * 16 + lane * 8;
  const short* AgB = AgA + 8 * PS;
  const short* BgA = Bt + ((size_t)(bN >> 4) + w) * PS + (size_t)kbeg * 16 + lane * 8;
  const short* BgB = BgA + 8 * PS;

  constexpr int KT = KSL / 64;           // K-tiles of 64 (>= 2)

  // LDS map (shorts): buf(t&1)*32768 + {A:0, B:16384} + kh*8192 + panel*512
  auto STAGE_Q = [&](int t, int qq) {    // quarter qq: 0:A-kh0 1:B-kh0 2:A-kh1 3:B-kh1
    const size_t go = (size_t)t * 1024 + (size_t)(qq >> 1) * 512;
    short* d = sLds + ((t & 1) << 15) + ((qq & 1) << 14) + ((qq >> 1) << 13) + w * 512;
    const short* g0 = (qq & 1) ? BgA : AgA;   // panel w
    const short* g1 = (qq & 1) ? BgB : AgB;   // panel w+8
    gld_lds16(g0 + go, d);
    gld_lds16(g1 + go, d + 4096);
  };

  const int aoff = wr * 4096 + quad * 128 + m * 8;           // + rt*512 + kh*8192
  const int boff = 16384 + wc * 2048 + quad * 128 + m * 8;   // + ct*512 + kh*8192

  bf16x8 aA[4], aB[4], bA[4], bB[4];

  // prologue: tile 0 fully staged; kh0 half waited; G0(0) issued
  STAGE_Q(0, 0); STAGE_Q(0, 1); STAGE_Q(0, 2); STAGE_Q(0, 3);
  asm volatile("s_waitcnt vmcnt(4)" ::: "memory");   // Q(0,0),Q(0,1) landed (mine)
  asm volatile("s_barrier" ::: "memory");            // B_A(0)
  {
    const short* bs = sLds;
#pragma unroll
    for (int rt = 0; rt < 4; ++rt) aA[rt] = *(const bf16x8*)(bs + aoff + rt * 512);
#pragma unroll
    for (int ct = 0; ct < 4; ++ct) bA[ct] = *(const bf16x8*)(bs + boff + ct * 512);
    if (KT > 1) STAGE_Q(1, 0);
    __builtin_amdgcn_sched_barrier(0);
  }

#pragma unroll 1
  for (int t = 0; t < KT; ++t) {
    const short* bs = sLds + ((t & 1) << 15);
    const bool pf = (t + 1 < KT);

    // ---- phase B: issue G1(t) | stage Q(t+1,1) | vmcnt | M0 (G0 ops, counted lgkm)
#pragma unroll
    for (int rt = 0; rt < 4; ++rt) aB[rt] = *(const bf16x8*)(bs + aoff + (4 + rt) * 512);
    if (pf) {
      STAGE_Q(t + 1, 1);
      asm volatile("s_waitcnt vmcnt(4)" ::: "memory");   // Q(t,2),Q(t,3) landed
    } else {
      asm volatile("s_waitcnt vmcnt(0)" ::: "memory");   // tail: last 4 stages
    }
    __builtin_amdgcn_sched_barrier(0);
    __builtin_amdgcn_s_setprio(1);
#pragma unroll
    for (int rt = 0; rt < 4; ++rt)
#pragma unroll
      for (int ct = 0; ct < 4; ++ct)
        acc[rt][ct] = __builtin_amdgcn_mfma_f32_16x16x32_bf16(aA[rt], bA[ct], acc[rt][ct], 0, 0, 0);
    __builtin_amdgcn_s_setprio(0);
    __builtin_amdgcn_sched_barrier(0);

    // ---- phase C: lgkm0+B_B(t) | issue G2(t) | stage Q(t+1,2) | M1 (G1+bA)
    asm volatile("s_waitcnt lgkmcnt(0)" ::: "memory");   // G1 retired (all reads done)
    asm volatile("s_barrier" ::: "memory");              // B_B(t): kh1 landed globally
#pragma unroll
    for (int rt = 0; rt < 4; ++rt) aA[rt] = *(const bf16x8*)(bs + 8192 + aoff + rt * 512);
#pragma unroll
    for (int ct = 0; ct < 4; ++ct) bB[ct] = *(const bf16x8*)(bs + 8192 + boff + ct * 512);
    if (pf) STAGE_Q(t + 1, 2);
    __builtin_amdgcn_sched_barrier(0);
    __builtin_amdgcn_s_setprio(1);
#pragma unroll
    for (int rt = 0; rt < 4; ++rt)
#pragma unroll
      for (int ct = 0; ct < 4; ++ct)
        acc[4 + rt][ct] = __builtin_amdgcn_mfma_f32_16x16x32_bf16(aB[rt], bA[ct], acc[4 + rt][ct], 0, 0, 0);
    __builtin_amdgcn_s_setprio(0);
    __builtin_amdgcn_sched_barrier(0);

    // ---- phase D: issue G3(t) | stage Q(t+1,3) | vmcnt | M2 (G2 ops, counted lgkm)
#pragma unroll
    for (int rt = 0; rt < 4; ++rt) aB[rt] = *(const bf16x8*)(bs + 8192 + aoff + (4 + rt) * 512);
    if (pf) {
      STAGE_Q(t + 1, 3);
      asm volatile("s_waitcnt vmcnt(4)" ::: "memory");   // Q(t+1,0),Q(t+1,1) landed
    }
    __builtin_amdgcn_sched_barrier(0);
    __builtin_amdgcn_s_setprio(1);
#pragma unroll
    for (int rt = 0; rt < 4; ++rt)
#pragma unroll
      for (int ct = 0; ct < 4; ++ct)
        acc[rt][ct] = __builtin_amdgcn_mfma_f32_16x16x32_bf16(aA[rt], bB[ct], acc[rt][ct], 0, 0, 0);
    __builtin_amdgcn_s_setprio(0);
    __builtin_amdgcn_sched_barrier(0);

    // ---- phase A(t+1): lgkm0+B_A | issue G0(t+1) | stage Q(t+2,0)
    if (pf) {
      asm volatile("s_waitcnt lgkmcnt(0)" ::: "memory"); // G3 retired: WAR-safe
      asm volatile("s_barrier" ::: "memory");            // B_A(t+1)
      const short* bs2 = sLds + (((t + 1) & 1) << 15);
#pragma unroll
      for (int rt = 0; rt < 4; ++rt) aA[rt] = *(const bf16x8*)(bs2 + aoff + rt * 512);
#pragma unroll
      for (int ct = 0; ct < 4; ++ct) bA[ct] = *(const bf16x8*)(bs2 + boff + ct * 512);
      if (t + 2 < KT) STAGE_Q(t + 2, 0);
      __builtin_amdgcn_sched_barrier(0);
    }
    // ---- M3(t): G3 x G2's B (operands already retired or auto-waited)
    __builtin_amdgcn_s_setprio(1);
#pragma unroll
    for (int rt = 0; rt < 4; ++rt)
#pragma unroll
      for (int ct = 0; ct < 4; ++ct)
        acc[4 + rt][ct] = __builtin_amdgcn_mfma_f32_16x16x32_bf16(aB[rt], bB[ct], acc[4 + rt][ct], 0, 0, 0);
    __builtin_amdgcn_s_setprio(0);
    __builtin_amdgcn_sched_barrier(0);
  }

  const int rowbase = bM + wr * 128;
  const int colbase = bN + wc * 64;

  if constexpr (MODE == 0) {
    // paired in_proj epilogue: even/odd ct frags = xi/g at the same phi.
    // newcolE bit4 == 0 always (colbase mult of 64, cp*32, m<16).
    short* xid = (short*)out0;
    short* prd = (short*)out1;
#pragma unroll
    for (int cp = 0; cp < 2; ++cp) {                  // frag pair (2cp, 2cp+1)
      const int newcolE = colbase + cp * 32 + m;
      const int phi = ((newcolE >> 5) << 4) | (newcolE & 15);   // 0..2047
      const float bxi = bias[phi];
      const float bg  = bias[DINNER + phi];
#pragma unroll
      for (int rt = 0; rt < 8; ++rt) {
        const size_t rowPan = ((size_t)(rowbase >> 4) + rt) << 8;   // *256 chunks
        const size_t base = ((rowPan + (phi >> 3)) << 7) + (phi & 7) + ((size_t)quad * 32);
#pragma unroll
        for (int reg = 0; reg < 4; ++reg) {
          const float xv = silu_f(acc[rt][2 * cp][reg] + bxi);
          const float gv = silu_f(acc[rt][2 * cp + 1][reg] + bg);
          xid[base + reg * 8] = f2bf(xv);
          prd[base + reg * 8] = f2bf(xv * gv);
        }
      }
    }
  } else {
    // raw bf16 partials, row-major stride N, +z slice offset
    constexpr int N = NT * 256;
    short* dst = (short*)out0 + (size_t)z * MROWS * N;
#pragma unroll
    for (int rt = 0; rt < 8; ++rt)
#pragma unroll
      for (int ct = 0; ct < 4; ++ct) {
        const int col = colbase + ct * 16 + m;
#pragma unroll
        for (int reg = 0; reg < 4; ++reg) {
          const int r = rowbase + rt * 16 + quad * 4 + reg;
          dst[(size_t)r * N + col] = f2bf(acc[rt][ct][reg]);
        }
      }
  }
}

// ---------------- skinny xp GEMM: bx partials = xi @ W_xp (fp32) -------------
// N=64, K=2048 split-K=2 -> 256 blocks x 256 thr (4 waves). Block = 64 rows
// (4 A-panels, one per wave) x 64 cols (4 B-panels, shared). Double-buffered
// LDS (2 x 16KB), 1-ahead prefetch, counted vmcnt(4). Writes fully-parallel
// fp32 partials bxp[z][8192][64]; scans add the two slices + b_xp.
__global__ __launch_bounds__(256) void xp_gemm(const short* __restrict__ xi,
                                               const short* __restrict__ Bxp,
                                               float* __restrict__ bxp) {
  __shared__ __attribute__((aligned(16))) short sA[2][4096];
  __shared__ __attribute__((aligned(16))) short sB[2][4096];
  const int tid = threadIdx.x, lane = tid & 63, w = tid >> 6;
  const int m = lane & 15, quad = lane >> 4;
  const int z = blockIdx.x >> 7;            // K-slice
  const int rb = (blockIdx.x & 127) * 64;   // row base
  const size_t PS = (size_t)2048 * 16;      // panel stride (shorts)
  const short* Ag = xi  + ((size_t)(rb >> 4) + w) * PS + (size_t)z * 1024 * 16 + lane * 8;
  const short* Bg = Bxp + (size_t)w * PS + (size_t)z * 1024 * 16 + lane * 8;
  floatx4 acc[4] = {};
  auto STAGE = [&](int t) {                 // 4 gld_lds per wave
    const size_t go = (size_t)t * 1024;     // 64 k -> 1024 shorts per panel
    short* da = sA[t & 1] + w * 1024;
    short* db = sB[t & 1] + w * 1024;
    gld_lds16(Ag + go, da); gld_lds16(Ag + go + 512, da + 512);
    gld_lds16(Bg + go, db); gld_lds16(Bg + go + 512, db + 512);
  };
  STAGE(0);
#pragma unroll 1
  for (int t = 0; t < 16; ++t) {
    __builtin_amdgcn_s_barrier();          // all reads of buf (t+1)&1 retired
    if (t + 1 < 16) {
      STAGE(t + 1);                         // outstanding: tile t (4) + t+1 (4)
      asm volatile("s_waitcnt vmcnt(4)" ::: "memory");   // tile t landed
    } else {
      asm volatile("s_waitcnt vmcnt(0)" ::: "memory");
    }
    __builtin_amdgcn_s_barrier();          // tile t visible to all waves
    const short* a0 = sA[t & 1] + w * 1024 + quad * 128 + m * 8;
    const short* b0 = sB[t & 1] + quad * 128 + m * 8;
#pragma unroll
    for (int kh = 0; kh < 2; ++kh) {
      bf16x8 a = *(const bf16x8*)(a0 + kh * 512);
#pragma unroll
      for (int ct = 0; ct < 4; ++ct) {
        bf16x8 b = *(const bf16x8*)(b0 + ct * 1024 + kh * 512);
        acc[ct] = __builtin_amdgcn_mfma_f32_16x16x32_bf16(a, b, acc[ct], 0, 0, 0);
      }
    }
  }
  float* dst = bxp + (size_t)z * MROWS * DSTATE;
#pragma unroll
  for (int ct = 0; ct < 4; ++ct)
#pragma unroll
    for (int reg = 0; reg < 4; ++reg)
      dst[(size_t)(rb + w * 16 + quad * 4 + reg) * DSTATE + ct * 16 + m] = acc[ct][reg];
}

// ---------------- split-K combine epilogues ----------------------------------
// G2: one wave per row; p[2][8192][1024] bf16 dt-partials -> md_sum
__global__ void g2_epilogue(const short* __restrict__ p, const float* __restrict__ b_dt,
                            float* __restrict__ md_sum) {
  const int row = blockIdx.x * 4 + (threadIdx.x >> 6);
  const int lane = threadIdx.x & 63;
  const size_t base0 = (size_t)row * 1024;
  const size_t base1 = base0 + (size_t)MROWS * 1024;
  short8 a0 = *(const short8*)(p + base0 + lane * 16);
  short8 a1 = *(const short8*)(p + base0 + lane * 16 + 8);
  short8 c0 = *(const short8*)(p + base1 + lane * 16);
  short8 c1 = *(const short8*)(p + base1 + lane * 16 + 8);
  float s = 0.f;
#pragma unroll
  for (int j = 0; j < 8; ++j) {
    s += softplus_f(bf2f(a0[j]) + bf2f(c0[j]) + b_dt[lane * 16 + j]);
    s += softplus_f(bf2f(a1[j]) + bf2f(c1[j]) + b_dt[lane * 16 + 8 + j]);
  }
  s += __shfl_xor(s, 1);  s += __shfl_xor(s, 2);  s += __shfl_xor(s, 4);
  s += __shfl_xor(s, 8);  s += __shfl_xor(s, 16); s += __shfl_xor(s, 32);
  if (lane == 0) md_sum[row] = s;
}

// G4: out = s_sum*(p0 + p1) + b_out + x*D   (fp32 row-major [8192,1024])
// s_sum applied here instead of a separate ymul kernel: out[r] =
// s[r]*((xi*g)[r] @ W_out) by linearity of matmul in A-rows.
__global__ void g4_epilogue(const short* __restrict__ p, const float* __restrict__ b_out,
                            const float* __restrict__ x, const float* __restrict__ Dv,
                            const float* __restrict__ s_sum, float* __restrict__ out) {
  const int r = blockIdx.x, c = threadIdx.x * 4;
  const float s = s_sum[r];
  const size_t o = (size_t)r * DMODEL + c;
  short4 a0 = *(const short4*)(p + o);
  short4 a1 = *(const short4*)(p + (size_t)MROWS * DMODEL + o);
  float4 xv = *(const float4*)(x + o);
  float4 ov;
  ov.x = s * (bf2f(a0.x) + bf2f(a1.x)) + b_out[c + 0] + xv.x * Dv[c + 0];
  ov.y = s * (bf2f(a0.y) + bf2f(a1.y)) + b_out[c + 1] + xv.y * Dv[c + 1];
  ov.z = s * (bf2f(a0.z) + bf2f(a1.z)) + b_out[c + 2] + xv.z * Dv[c + 2];
  ov.w = s * (bf2f(a0.w) + bf2f(a1.w)) + b_out[c + 3] + xv.w * Dv[c + 3];
  *(float4*)(out + o) = ov;
}

// ---------------- chunked selective scan (2 phases) --------------------------
// bx value = bxp[0][row][n] + bxp[1][row][n] + b_xp[n] (fp32 split-K partials)
__global__ void scan_phase1(const float* __restrict__ md_sum, const float* __restrict__ A_log,
                            const float* __restrict__ bxp, const float* __restrict__ b_xp,
                            float* __restrict__ chunk_prod, float* __restrict__ chunk_end) {
  const int n = threadIdx.x;                // 0..63 (state dim)
  const int c = blockIdx.x & (NCHUNK - 1);  // chunk
  const int b = blockIdx.x >> 6;            // batch
  const float An = -__expf(A_log[n]);
  const float bxn = b_xp[n];
  const float* bx0 = bxp;
  const float* bx1 = bxp + (size_t)MROWS * DSTATE;
  float prod = 1.f, st = 0.f;
  const int t0 = c * LCHUNK;
#pragma unroll 4
  for (int i = 0; i < LCHUNK; ++i) {
    const int t = t0 + i;
    const float md = md_sum[b * SEQ + t] * (1.f / DMODEL);
    const float a = __expf(An * md);
    const size_t idx = ((size_t)(b * SEQ + t)) * DSTATE + n;
    st = a * st + (bx0[idx] + bx1[idx] + bxn);
    prod *= a;
  }
  chunk_prod[(b * NCHUNK + c) * DSTATE + n] = prod;
  chunk_end [(b * NCHUNK + c) * DSTATE + n] = st;
}

// phase3: redo own chunk-prefix, recompute a=exp(An*md), emit s_sum
__global__ void scan_phase3(const float* __restrict__ md_sum, const float* __restrict__ A_log,
                            const float* __restrict__ bxp, const float* __restrict__ b_xp,
                            const float* __restrict__ chunk_prod,
                            const float* __restrict__ chunk_end,
                            float* __restrict__ s_sum) {
  const int n = threadIdx.x;
  const int c = blockIdx.x & (NCHUNK - 1);
  const int b = blockIdx.x >> 6;
  const float An = -__expf(A_log[n]);
  const float bxn = b_xp[n];
  const float* bx0 = bxp;
  const float* bx1 = bxp + (size_t)MROWS * DSTATE;
  float st = 0.f;
#pragma unroll 4
  for (int cc = 0; cc < c; ++cc) {
    const size_t idx = ((size_t)(b * NCHUNK + cc)) * DSTATE + n;
    st = chunk_prod[idx] * st + chunk_end[idx];
  }
  const int t0 = c * LCHUNK;
#pragma unroll 4
  for (int i = 0; i < LCHUNK; ++i) {
    const int t = t0 + i;
    const float md = md_sum[b * SEQ + t] * (1.f / DMODEL);
    const float a = __expf(An * md);
    const size_t idx = ((size_t)(b * SEQ + t)) * DSTATE + n;
    st = a * st + (bx0[idx] + bx1[idx] + bxn);
    float v = st;
    v += __shfl_xor(v, 32); v += __shfl_xor(v, 16); v += __shfl_xor(v, 8);
    v += __shfl_xor(v, 4);  v += __shfl_xor(v, 2);  v += __shfl_xor(v, 1);
    if (n == 0) s_sum[b * SEQ + t] = v;
  }
}

// ---------------- launch ------------------------------------------------------
extern "C" void kernel_launch(void* const* d_in, const int* in_sizes, int n_in,
                              void* d_out, int out_size, void* d_ws, size_t ws_size,
                              hipStream_t stream) {
  const float* x     = (const float*)d_in[0];
  const float* W_in  = (const float*)d_in[1];
  const float* b_in  = (const float*)d_in[2];
  const float* W_xp  = (const float*)d_in[3];
  const float* b_xp  = (const float*)d_in[4];
  const float* W_dt  = (const float*)d_in[5];
  const float* b_dt  = (const float*)d_in[6];
  const float* W_out = (const float*)d_in[7];
  const float* b_out = (const float*)d_in[8];
  const float* A_log = (const float*)d_in[9];
  const float* Dv    = (const float*)d_in[10];

  char* ws = (char*)d_ws;
  size_t off = 0;
  auto alloc = [&](size_t bytes) -> void* {
    void* p = (void*)(ws + off);
    off += (bytes + 255) & ~(size_t)255;
    return p;
  };
  short* x_bf    = (short*)alloc((size_t)MROWS * DMODEL * 2);
  short* Wt_in   = (short*)alloc((size_t)4096 * 1024 * 2);
  short* Bcat    = (short*)alloc((size_t)NCAT * DINNER * 2);
  short* Wt_out  = (short*)alloc((size_t)1024 * 2048 * 2);
  short* xi      = (short*)alloc((size_t)MROWS * DINNER * 2);   // also G4 partials
  short* prod    = (short*)alloc((size_t)MROWS * DINNER * 2);   // silu(xi)*silu(g)
  short* p2      = (short*)alloc((size_t)2 * MROWS * 1024 * 2); // G2 dt partials
  float* md_sum  = (float*)alloc((size_t)MROWS * 4);
  float* bxp     = (float*)alloc((size_t)2 * MROWS * DSTATE * 4); // xp partials
  float* cprod   = (float*)alloc((size_t)2 * NCHUNK * DSTATE * 4);
  float* cend    = (float*)alloc((size_t)2 * NCHUNK * DSTATE * 4);
  float* s_sum   = (float*)alloc((size_t)MROWS * 4);

  // fused pre-pass: x->bf16 (panel-staged) + all 4 weight transposes
  // (W_in transposed with the xi/g column-pairing remap)
  prepass_kernel<<<PP4, 256, 0, stream>>>(x, x_bf, W_in, Wt_in, W_dt, W_xp, Bcat, W_out, Wt_out);

  // GEMM1: in_proj, paired epilogue -> xi + prod (ymul folded in)
  gemm256<0, 1024, 1024, 16, 1><<<512, 512, 0, stream>>>(x_bf, Wt_in, b_in, xi, prod);
  // GEMM2-dt: 256^2 pipeline, split-K=2, N=1024 -> one clean round (256 blocks)
  gemm256<1, 2048, 1024, 4, 2><<<256, 512, 0, stream>>>(xi, Bcat, nullptr, p2, nullptr);
  // GEMM2-xp: skinny N=64, fp32 partials straight into bxp
  xp_gemm<<<256, 256, 0, stream>>>(xi, Bcat + (size_t)1024 * DINNER, bxp);
  // combine dt partials -> softplus rowsum
  g2_epilogue<<<MROWS / 4, 256, 0, stream>>>(p2, b_dt, md_sum);
  // selective scan (phase3 self-computes its chunk prefix)
  scan_phase1<<<2 * NCHUNK, DSTATE, 0, stream>>>(md_sum, A_log, bxp, b_xp, cprod, cend);
  scan_phase3<<<2 * NCHUNK, DSTATE, 0, stream>>>(md_sum, A_log, bxp, b_xp, cprod, cend, s_sum);
  // GEMM4: P = prod @ W_out, split-K=2 partials into xi's slot
  gemm256<1, 2048, 1024, 4, 2><<<256, 512, 0, stream>>>(prod, Wt_out, nullptr, xi, nullptr);
  // epilogue applies s_sum scale + b_out + x*D
  g4_epilogue<<<MROWS, 256, 0, stream>>>(xi, b_out, x, Dv, s_sum, (float*)d_out);
}